// Round 7
// baseline (475.052 us; speedup 1.0000x reference)
//
#include <hip/hip_runtime.h>

#define Bn 512
#define Ln 2048
#define Kn 19
#define NEGV (-1000.0f)
#define START_IDn 17
#define PAD_IDn 18
#define SEG 64               // checkpoint / staging segment (steps)
#define PBYTES 79691776u     // 512*2048*19*4

// ---------------------------------------------------------------------------
// R7 = R6 resubmit (container failure, no access-audit finding => infra-flake
// hypothesis) + defensive len clamp.
//   crf_fwd — serial DP with SGPR broadcast (v_readlane): no per-step LDS
//             round-trip, no per-step mask (len wave-uniform, exact-steps).
//   crf_rec — bit-exact backpointer recompute at high occupancy (R5-proven).
//   crf_bwd — function-composition backtrace (R5-proven).
// Evidence: R5 confirmed cadence model (time ∝ wave-instr count, ~6.7
// cy/instr solo); R5 fwd = 277 cy/step ≈ 83 issue + ~190 LDS dp round-trip.
// ---------------------------------------------------------------------------

__global__ __launch_bounds__(64, 1) void crf_fwd(
    const float* __restrict__ P, const float* __restrict__ T,
    const int* __restrict__ mask, float* __restrict__ dpck,
    float* __restrict__ dpfin, int* __restrict__ lens)
{
    const int lane = threadIdx.x;
    const int b = blockIdx.x;                 // one batch per wave/block
    const int cc = (lane < Kn) ? lane : (Kn - 1);

    float Trow[Kn];
#pragma unroll
    for (int p = 0; p < Kn; ++p) Trow[p] = T[cc * Kn + p];

    // length = popcount of contiguous-prefix mask row (64-lane cooperative)
    const int* mrow = mask + (size_t)b * Ln;
    int sum = 0;
#pragma unroll
    for (int j = 0; j < 8; ++j) {
        int4 v = *(const int4*)(mrow + j * 256 + lane * 4);
        sum += v.x + v.y + v.z + v.w;
    }
#pragma unroll
    for (int k = 1; k < 64; k <<= 1) sum += __shfl_xor(sum, k, 64);
    int lenr = __builtin_amdgcn_readfirstlane(sum);
    if (lenr < 1) lenr = 1;                   // defensive clamp (spec: 1..Ln)
    if (lenr > Ln) lenr = Ln;
    const int len = lenr;
    if (lane == 0) lens[b] = len;

    __shared__ float ebuf[2][1232];           // 19*64=1216 used + pad

    float mydp = (lane == START_IDn) ? 0.0f : NEGV;

    const unsigned bbyte = (unsigned)b * (Ln * Kn * 4u);
    const unsigned limit = PBYTES - 16;
    const char* Pc = (const char*)P;
    float4 r[5];

    // 4864 B of emissions per 64-step segment = 304 float4; 64 lanes x 5,
    // indices >= 304 clamped (duplicate same-data writes, once per segment).
#define STAGE_LOAD(ci)                                                         \
    { unsigned sb_ = bbyte + (unsigned)(ci) * 4864u;                           \
      _Pragma("unroll")                                                        \
      for (int i_ = 0; i_ < 5; ++i_) {                                         \
          unsigned idx_ = (unsigned)lane + 64u * (unsigned)i_;                 \
          if (idx_ > 303u) idx_ = 303u;                                        \
          unsigned o_ = sb_ + idx_ * 16u;                                      \
          if (o_ > limit) o_ = limit;                                          \
          r[i_] = *(const float4*)(Pc + o_);                                   \
      } }
#define STAGE_WRITE(nb)                                                        \
    { _Pragma("unroll")                                                        \
      for (int i_ = 0; i_ < 5; ++i_) {                                         \
          unsigned idx_ = (unsigned)lane + 64u * (unsigned)i_;                 \
          if (idx_ > 303u) idx_ = 303u;                                        \
          *(float4*)((char*)&ebuf[nb][0] + idx_ * 16u) = r[i_];                \
      } }

    // One Viterbi step: broadcast dp via v_readlane (SGPRs), cand = dp[p] +
    // T[c][p] (exact reference add order), best = 9x v_max3, dp = best + emit.
#define RL(p) __int_as_float(__builtin_amdgcn_readlane(mi_, (p)))
#define STEP_BODY(EXPR_E)                                                      \
    { const float e_ = (EXPR_E);                                               \
      const int mi_ = __float_as_int(mydp);                                    \
      float c0_  = RL(0)  + Trow[0];  float c1_  = RL(1)  + Trow[1];           \
      float c2_  = RL(2)  + Trow[2];  float c3_  = RL(3)  + Trow[3];           \
      float c4_  = RL(4)  + Trow[4];  float c5_  = RL(5)  + Trow[5];           \
      float c6_  = RL(6)  + Trow[6];  float c7_  = RL(7)  + Trow[7];           \
      float c8_  = RL(8)  + Trow[8];  float c9_  = RL(9)  + Trow[9];           \
      float c10_ = RL(10) + Trow[10]; float c11_ = RL(11) + Trow[11];          \
      float c12_ = RL(12) + Trow[12]; float c13_ = RL(13) + Trow[13];          \
      float c14_ = RL(14) + Trow[14]; float c15_ = RL(15) + Trow[15];          \
      float c16_ = RL(16) + Trow[16]; float c17_ = RL(17) + Trow[17];          \
      float c18_ = RL(18) + Trow[18];                                          \
      float t0_ = fmaxf(fmaxf(c0_,  c1_),  c2_);                               \
      float t1_ = fmaxf(fmaxf(c3_,  c4_),  c5_);                               \
      float t2_ = fmaxf(fmaxf(c6_,  c7_),  c8_);                               \
      float t3_ = fmaxf(fmaxf(c9_,  c10_), c11_);                              \
      float t4_ = fmaxf(fmaxf(c12_, c13_), c14_);                              \
      float t5_ = fmaxf(fmaxf(c15_, c16_), c17_);                              \
      float u0_ = fmaxf(fmaxf(t0_, t1_), t2_);                                 \
      float u1_ = fmaxf(fmaxf(t3_, t4_), c18_);                                \
      float best_ = fmaxf(fmaxf(u0_, u1_), t5_);                               \
      mydp = best_ + e_; }

    int buf = 0;
    STAGE_LOAD(0);
    STAGE_WRITE(0);

    const int nfull = len >> 6;
    const int rem = len & 63;

    for (int seg = 0; seg < nfull; ++seg) {
        if (lane < Kn)
            dpck[((unsigned)b * 32u + (unsigned)seg) * (unsigned)Kn + (unsigned)lane] = mydp;
        STAGE_LOAD(seg + 1);                  // prefetch next segment
        const float* ebl = &ebuf[buf][0];
        for (int t8 = 0; t8 < SEG; t8 += 8) {
#pragma unroll
            for (int u = 0; u < 8; ++u) STEP_BODY(ebl[(t8 + u) * Kn + cc]);
        }
        STAGE_WRITE(buf ^ 1);
        buf ^= 1;
    }
    if (rem) {
        if (lane < Kn)
            dpck[((unsigned)b * 32u + (unsigned)nfull) * (unsigned)Kn + (unsigned)lane] = mydp;
        const float* ebl = &ebuf[buf][0];
        for (int tt = 0; tt < rem; ++tt) STEP_BODY(ebl[tt * Kn + cc]);
    }
    if (lane < Kn) dpfin[b * Kn + lane] = mydp;   // frozen final DP
#undef STAGE_LOAD
#undef STAGE_WRITE
#undef STEP_BODY
#undef RL
}

// ---------------------------------------------------------------------------
// Recompute backpointers (R5-proven): task = (batch, segment); 32-lane
// half-wave per task, 8 tasks per 256-thread block; bit-exact recompute of
// the DP candidates + first-index argmax; bulk choice flush.
// ---------------------------------------------------------------------------
#define DP_CORE(BASE)                                                          \
    float4 q0 = *(const float4*)((BASE) + 0);                                  \
    float4 q1 = *(const float4*)((BASE) + 4);                                  \
    float4 q2 = *(const float4*)((BASE) + 8);                                  \
    float4 q3 = *(const float4*)((BASE) + 12);                                 \
    float4 q4 = *(const float4*)((BASE) + 16); /* .w junk, unused */           \
    float cand[Kn];                                                            \
    cand[0]  = q0.x + Trow[0];  cand[1]  = q0.y + Trow[1];                     \
    cand[2]  = q0.z + Trow[2];  cand[3]  = q0.w + Trow[3];                     \
    cand[4]  = q1.x + Trow[4];  cand[5]  = q1.y + Trow[5];                     \
    cand[6]  = q1.z + Trow[6];  cand[7]  = q1.w + Trow[7];                     \
    cand[8]  = q2.x + Trow[8];  cand[9]  = q2.y + Trow[9];                     \
    cand[10] = q2.z + Trow[10]; cand[11] = q2.w + Trow[11];                    \
    cand[12] = q3.x + Trow[12]; cand[13] = q3.y + Trow[13];                    \
    cand[14] = q3.z + Trow[14]; cand[15] = q3.w + Trow[15];                    \
    cand[16] = q4.x + Trow[16]; cand[17] = q4.y + Trow[17];                    \
    cand[18] = q4.z + Trow[18];                                                \
    float m0 = fmaxf(fmaxf(cand[0],  cand[1]),  cand[2]);                      \
    float m1 = fmaxf(fmaxf(cand[3],  cand[4]),  cand[5]);                      \
    float m2 = fmaxf(fmaxf(cand[6],  cand[7]),  cand[8]);                      \
    float m3 = fmaxf(fmaxf(cand[9],  cand[10]), cand[11]);                     \
    float m4 = fmaxf(fmaxf(cand[12], cand[13]), cand[14]);                     \
    float m5 = fmaxf(fmaxf(cand[15], cand[16]), cand[17]);                     \
    float n0 = fmaxf(fmaxf(m0, m1), m2);                                       \
    float n1 = fmaxf(fmaxf(m3, m4), cand[18]);                                 \
    float best = fmaxf(fmaxf(n0, n1), m5);

__global__ __launch_bounds__(256) void crf_rec(
    const float* __restrict__ P, const float* __restrict__ T,
    const float* __restrict__ dpck, const int* __restrict__ lens,
    unsigned char* __restrict__ choice)
{
    const int tid = threadIdx.x;
    const int halfid = tid >> 5;
    const int c = tid & 31;
    const int cc = (c < Kn) ? c : (Kn - 1);
    const int task = blockIdx.x * 8 + halfid;   // < 16384
    const int b = task >> 5;
    const int seg = task & 31;
    const int t0 = seg * SEG;
    const int len = lens[b];
    if (t0 >= len) return;                      // rows never read by backtrace

    __shared__ float dp[8][32];
    __shared__ __align__(16) unsigned char cbuf[8][SEG * Kn];  // 8 x 1216

    float Trow[Kn];
#pragma unroll
    for (int p = 0; p < Kn; ++p) Trow[p] = T[cc * Kn + p];

    float mydp = (c < Kn) ? dpck[((unsigned)b * 32u + (unsigned)seg) * (unsigned)Kn + (unsigned)c]
                          : NEGV;
    dp[halfid][c] = mydp;

    const float* prow = P + (size_t)b * Ln * Kn + (size_t)t0 * Kn;

    // rolling emission prefetch (depth 8)
    float eb[8];
#pragma unroll
    for (int u = 0; u < 8; ++u) eb[u] = prow[u * Kn + cc];

    for (int tt = 0; tt < SEG; tt += 8) {
#pragma unroll
        for (int u = 0; u < 8; ++u) {
            const int t = t0 + tt + u;
            const float e = eb[u];
            const float* base_ = &dp[halfid][0];
            DP_CORE(base_)
            float nd = best + e;
            mydp = (t < len) ? nd : mydp;
            dp[halfid][c] = mydp;

            // first-index argmax (jnp.argmax tie-break), exact equality
            int arg = Kn - 1;
#pragma unroll
            for (int p = Kn - 2; p >= 0; --p)
                arg = (cand[p] == best) ? p : arg;
            if (c < Kn) cbuf[halfid][(tt + u) * Kn + c] = (unsigned char)arg;

            // prefetch emission for local step tt+u+8 (clamped in-bounds)
            int tn = tt + u + 8;
            int tloc = (t0 + tn < Ln) ? tn : (Ln - 1 - t0);
            eb[u] = prow[tloc * Kn + cc];
        }
    }
    // bulk flush this segment's backpointers (steps >= len garbage, unread)
    {
        const int4* s = (const int4*)&cbuf[halfid][0];
        int4* d = (int4*)(choice + (size_t)b * Ln * Kn + (size_t)t0 * Kn);
        for (int i = c; i < (SEG * Kn) / 16; i += 32) d[i] = s[i];
    }
}

// ---------------------------------------------------------------------------
// Backtrace (R5-proven): exact integer function-composition scan.
// ---------------------------------------------------------------------------
__global__ __launch_bounds__(384, 1) void crf_bwd(
    const float* __restrict__ T, const unsigned char* __restrict__ choice,
    const float* __restrict__ dpfin, const int* __restrict__ lens,
    int* __restrict__ out)
{
    __shared__ unsigned char comp[Ln * Kn];   // 38912 B
    __shared__ int vchain[17];
    __shared__ int s_last, s_len;

    const int b = blockIdx.x;
    const int tid = threadIdx.x;

    {
        const int4* src = (const int4*)(choice + (size_t)b * Ln * Kn);
        int4* dst = (int4*)comp;
        for (int i = tid; i < (Ln * Kn) / 16; i += 384) dst[i] = src[i];
    }
    if (tid == 0) {
        s_len = lens[b];
        float bestv = dpfin[b * Kn + 0] + T[PAD_IDn * Kn + 0];
        int bl = 0;
        for (int ci = 1; ci < Kn; ++ci) {
            float v = dpfin[b * Kn + ci] + T[PAD_IDn * Kn + ci];
            if (v > bestv) { bestv = v; bl = ci; }
        }
        s_last = bl;
    }
    __syncthreads();
    const int len = s_len;

    // Phase 1: suffix-compose within each 128-step chunk, in place.
    {
        const int wv = tid >> 6;
        const int lane = tid & 63;
        const int ch = wv * 3 + lane / Kn;
        const int c = lane % Kn;
        if (lane < 3 * Kn && ch < 16) {
            int cur = c;
            const int tb = ch * 128 + 127;
            for (int i = 0; i < 128; ++i) {
                const int t = tb - i;
                int nv = comp[t * Kn + cur];   // cur <= 18 always: in-bounds
                cur = (t < len) ? nv : cur;
                comp[t * Kn + c] = cur;
            }
        }
    }
    __syncthreads();

    // Phase 2: chunk-boundary chain
    if (tid == 0) {
        int v = s_last;
        vchain[16] = v;
        for (int ch = 15; ch >= 0; --ch) {
            v = comp[ch * 128 * Kn + v];
            vchain[ch] = v;
        }
    }
    __syncthreads();

    // Phase 3: emit path
    const int last = s_last;
    int* orow = out + (size_t)b * Ln;
    for (int t = tid; t < Ln; t += 384) {
        int val;
        if (t >= len) {
            val = -1;
        } else if (t == Ln - 1) {
            val = last;
        } else {
            const int tp = t + 1;
            const int vc = vchain[(tp >> 7) + 1];
            val = comp[tp * Kn + vc];
        }
        orow[t] = val;
    }
}

// ---------------------------------------------------------------------------
extern "C" void kernel_launch(void* const* d_in, const int* in_sizes, int n_in,
                              void* d_out, int out_size, void* d_ws, size_t ws_size,
                              hipStream_t stream)
{
    const float* P    = (const float*)d_in[0];
    const float* T    = (const float*)d_in[1];
    const int*   mask = (const int*)d_in[2];
    int* out = (int*)d_out;

    // workspace layout — identical footprint to R1-R3/R5 (proven ok)
    const size_t choice_bytes = (size_t)Bn * Ln * Kn;            // 19,922,944
    unsigned char* choice = (unsigned char*)d_ws;
    float* dpfin = (float*)((char*)d_ws + choice_bytes);
    int* lens = (int*)((char*)d_ws + choice_bytes + (size_t)Bn * Kn * 4);

    // dpck (1,245,184 B) lives in d_out (4 MB of int32): written by crf_fwd,
    // read by crf_rec, then d_out fully overwritten by crf_bwd. Stream-ordered
    // (same pattern passed in R5).
    float* dpck = (float*)((char*)d_out + 2 * 1024 * 1024);

    crf_fwd<<<Bn, 64, 0, stream>>>(P, T, mask, dpck, dpfin, lens);
    crf_rec<<<(Bn * 32) / 8, 256, 0, stream>>>(P, T, dpck, lens, choice);
    crf_bwd<<<Bn, 384, 0, stream>>>(T, choice, dpfin, lens, out);
}

// Round 8
// 415.535 us; speedup vs baseline: 1.1432x; 1.1432x over previous
//
#include <hip/hip_runtime.h>

#define Bn 512
#define Ln 2048
#define Kn 19
#define NEGV (-1000.0f)
#define START_IDn 17
#define PAD_IDn 18
#define SEG 64               // checkpoint / staging segment (steps)
#define PBYTES 79691776u     // 512*2048*19*4

// ---------------------------------------------------------------------------
// R8 = R5's proven crf_fwd (236.6 µs; LDS-dp core — R7 showed readlane is
// strictly worse: 98 instr/step + same ~150cy broadcast stall) + leaner
// crf_rec (LDS-staged emissions, exact-length tail => no per-step mask,
// no per-step prefetch address math) + proven crf_bwd.
// ---------------------------------------------------------------------------

// Shared per-step core: cand[p] = dp[p] + Trow[p] (exact reference op order),
// best = depth-3 max tree (v_max3). Argmax only in crf_rec.
#define DP_CORE(BASE)                                                          \
    float4 q0 = *(const float4*)((BASE) + 0);                                  \
    float4 q1 = *(const float4*)((BASE) + 4);                                  \
    float4 q2 = *(const float4*)((BASE) + 8);                                  \
    float4 q3 = *(const float4*)((BASE) + 12);                                 \
    float4 q4 = *(const float4*)((BASE) + 16); /* .w junk, unused */           \
    float cand[Kn];                                                            \
    cand[0]  = q0.x + Trow[0];  cand[1]  = q0.y + Trow[1];                     \
    cand[2]  = q0.z + Trow[2];  cand[3]  = q0.w + Trow[3];                     \
    cand[4]  = q1.x + Trow[4];  cand[5]  = q1.y + Trow[5];                     \
    cand[6]  = q1.z + Trow[6];  cand[7]  = q1.w + Trow[7];                     \
    cand[8]  = q2.x + Trow[8];  cand[9]  = q2.y + Trow[9];                     \
    cand[10] = q2.z + Trow[10]; cand[11] = q2.w + Trow[11];                    \
    cand[12] = q3.x + Trow[12]; cand[13] = q3.y + Trow[13];                    \
    cand[14] = q3.z + Trow[14]; cand[15] = q3.w + Trow[15];                    \
    cand[16] = q4.x + Trow[16]; cand[17] = q4.y + Trow[17];                    \
    cand[18] = q4.z + Trow[18];                                                \
    float m0 = fmaxf(fmaxf(cand[0],  cand[1]),  cand[2]);                      \
    float m1 = fmaxf(fmaxf(cand[3],  cand[4]),  cand[5]);                      \
    float m2 = fmaxf(fmaxf(cand[6],  cand[7]),  cand[8]);                      \
    float m3 = fmaxf(fmaxf(cand[9],  cand[10]), cand[11]);                     \
    float m4 = fmaxf(fmaxf(cand[12], cand[13]), cand[14]);                     \
    float m5 = fmaxf(fmaxf(cand[15], cand[16]), cand[17]);                     \
    float n0 = fmaxf(fmaxf(m0, m1), m2);                                       \
    float n1 = fmaxf(fmaxf(m3, m4), cand[18]);                                 \
    float best = fmaxf(fmaxf(n0, n1), m5);

// ---------------------------------------------------------------------------
// crf_fwd — verbatim R5 (measured 236.6 µs, passed).
// ---------------------------------------------------------------------------
__global__ __launch_bounds__(64, 1) void crf_fwd(
    const float* __restrict__ P, const float* __restrict__ T,
    const int* __restrict__ mask, float* __restrict__ dpck,
    float* __restrict__ dpfin, int* __restrict__ lens)
{
    const int lane = threadIdx.x;
    const int half = lane >> 5;
    const int c = lane & 31;
    const int b = blockIdx.x * 2 + half;
    const int cc = (c < Kn) ? c : (Kn - 1);

    float Trow[Kn];
#pragma unroll
    for (int p = 0; p < Kn; ++p) Trow[p] = T[cc * Kn + p];

    // length = popcount of contiguous-prefix mask row
    const int* mrow = mask + (size_t)b * Ln;
    int sum = 0;
#pragma unroll
    for (int j = 0; j < Ln / 128; ++j) {
        int4 v = *(const int4*)(mrow + j * 128 + c * 4);
        sum += v.x + v.y + v.z + v.w;
    }
#pragma unroll
    for (int k = 1; k < 32; k <<= 1) sum += __shfl_xor(sum, k, 64);
    const int len = sum;
    if (c == 0) lens[b] = len;
    const int lenO = __shfl_xor(len, 32, 64);
    int maxlen = len > lenO ? len : lenO;
    int lmin = len < lenO ? len : lenO;
    lmin = __builtin_amdgcn_readfirstlane(lmin);
    int mlen = (maxlen + (SEG - 1)) & ~(SEG - 1);
    mlen = __builtin_amdgcn_readfirstlane(mlen);

    __shared__ float dp[2][32];
    __shared__ float ebuf[2][2][1280];   // [buf][half]; 64*19=1216 used + pad

    float mydp = (c == START_IDn) ? 0.0f : NEGV;
    dp[half][c] = mydp;

    const unsigned bbyte = (unsigned)b * (Ln * Kn * 4u);
    const unsigned limit = PBYTES - 16;
    const char* Pc = (const char*)P;
    float4 r[10];

#define STAGE_LOAD(ci)                                                         \
    { unsigned base_ = bbyte + (unsigned)(ci) * 4864u + ((unsigned)c << 4);    \
      _Pragma("unroll")                                                        \
      for (int i_ = 0; i_ < 10; ++i_) {                                        \
          unsigned o_ = base_ + (unsigned)i_ * 512u;                           \
          if (o_ > limit) o_ = limit;                                          \
          r[i_] = *(const float4*)(Pc + o_);                                   \
      } }
#define STAGE_WRITE(nb)                                                        \
    { float* d_ = &ebuf[nb][half][(unsigned)c << 2];                           \
      _Pragma("unroll")                                                        \
      for (int i_ = 0; i_ < 10; ++i_) *(float4*)(d_ + i_ * 128) = r[i_]; }

    int buf = 0;
    STAGE_LOAD(0);
    STAGE_WRITE(0);

    for (int t0 = 0; t0 < mlen; t0 += SEG) {
        // checkpoint: DP entering step t0 (includes initial DP at t0=0)
        if (c < Kn)
            dpck[((unsigned)b * 32u + (unsigned)(t0 >> 6)) * (unsigned)Kn + (unsigned)c] = mydp;
        STAGE_LOAD((t0 >> 6) + 1);       // prefetch next segment's emissions
        const float* ebl = &ebuf[buf][half][0];

        if (t0 + SEG <= lmin) {
            // fast path: every step strictly below both lengths — no mask
            for (int tt = 0; tt < SEG; tt += 8) {
#pragma unroll
                for (int u = 0; u < 8; ++u) {
                    const float e = ebl[(tt + u) * Kn + cc];
                    const float* base_ = &dp[half][0];
                    DP_CORE(base_)
                    mydp = best + e;
                    dp[half][c] = mydp;
                }
            }
        } else {
            for (int tt = 0; tt < SEG; tt += 8) {
#pragma unroll
                for (int u = 0; u < 8; ++u) {
                    const int t = t0 + tt + u;
                    const float e = ebl[(tt + u) * Kn + cc];
                    const float* base_ = &dp[half][0];
                    DP_CORE(base_)
                    float nd = best + e;
                    mydp = (t < len) ? nd : mydp;   // frozen past sequence end
                    dp[half][c] = mydp;
                }
            }
        }
        STAGE_WRITE(buf ^ 1);
        buf ^= 1;
    }
    if (c < Kn) dpfin[b * Kn + c] = mydp;
#undef STAGE_LOAD
#undef STAGE_WRITE
}

// ---------------------------------------------------------------------------
// crf_rec (R8-lean): task = (batch, segment); 32-lane half-wave per task,
// 8 tasks per 256-thread block. Emissions LDS-staged with coalesced float4
// (no per-step prefetch math); tail segment runs exactly rem = len-t0 steps
// => no per-step mask anywhere. Bit-exact recompute (same inputs, same op
// order) + first-index argmax; bulk choice flush.
// LDS: ebuf 8*4928 + cbuf 8*1216 + dp 8*128 = 49.7 KB -> ~3 blocks/CU.
// ---------------------------------------------------------------------------
__global__ __launch_bounds__(256) void crf_rec(
    const float* __restrict__ P, const float* __restrict__ T,
    const float* __restrict__ dpck, const int* __restrict__ lens,
    unsigned char* __restrict__ choice)
{
    const int tid = threadIdx.x;
    const int halfid = tid >> 5;
    const int c = tid & 31;
    const int cc = (c < Kn) ? c : (Kn - 1);
    const int task = blockIdx.x * 8 + halfid;   // < 16384
    const int b = task >> 5;
    const int seg = task & 31;
    const int t0 = seg * SEG;
    const int len = lens[b];
    if (t0 >= len) return;                      // rows never read by backtrace

    int rem = len - t0;                         // steps to execute (>=1)
    if (rem > SEG) rem = SEG;

    __shared__ float dp[8][32];
    __shared__ __align__(16) unsigned char cbuf[8][SEG * Kn];  // 8 x 1216
    __shared__ float ebuf[8][1232];             // 4864 B used + pad

    float Trow[Kn];
#pragma unroll
    for (int p = 0; p < Kn; ++p) Trow[p] = T[cc * Kn + p];

    // stage this segment's emissions: 304 float4; 32 lanes x 10, clamped
    {
        const unsigned sb = ((unsigned)b * (Ln * Kn * 4u)) + (unsigned)t0 * (Kn * 4u);
        const unsigned limit = PBYTES - 16;
        const char* Pc = (const char*)P;
        float4 rr[10];
#pragma unroll
        for (int i = 0; i < 10; ++i) {
            unsigned idx = (unsigned)c + 32u * (unsigned)i;
            if (idx > 303u) idx = 303u;
            unsigned o = sb + idx * 16u;
            if (o > limit) o = limit;
            rr[i] = *(const float4*)(Pc + o);
        }
        char* eb = (char*)&ebuf[halfid][0];
#pragma unroll
        for (int i = 0; i < 10; ++i) {
            unsigned idx = (unsigned)c + 32u * (unsigned)i;
            if (idx > 303u) idx = 303u;
            *(float4*)(eb + idx * 16u) = rr[i];
        }
    }

    float mydp = (c < Kn) ? dpck[((unsigned)b * 32u + (unsigned)seg) * (unsigned)Kn + (unsigned)c]
                          : NEGV;
    dp[halfid][c] = mydp;

    const float* ebl = &ebuf[halfid][0];
    for (int tt = 0; tt < rem; ++tt) {          // exact trip count: no mask
        const float e = ebl[tt * Kn + cc];
        const float* base_ = &dp[halfid][0];
        DP_CORE(base_)
        mydp = best + e;                        // every executed step has t<len
        dp[halfid][c] = mydp;

        // first-index argmax (jnp.argmax tie-break), exact equality
        int arg = Kn - 1;
#pragma unroll
        for (int p = Kn - 2; p >= 0; --p)
            arg = (cand[p] == best) ? p : arg;
        if (c < Kn) cbuf[halfid][tt * Kn + c] = (unsigned char)arg;
    }
    // bulk flush (rows >= rem hold stale/garbage bytes — never read)
    {
        const int4* s = (const int4*)&cbuf[halfid][0];
        int4* d = (int4*)(choice + (size_t)b * Ln * Kn + (size_t)t0 * Kn);
        for (int i = c; i < (SEG * Kn) / 16; i += 32) d[i] = s[i];
    }
}

// ---------------------------------------------------------------------------
// Backtrace (proven): exact integer function-composition scan.
// ---------------------------------------------------------------------------
__global__ __launch_bounds__(384, 1) void crf_bwd(
    const float* __restrict__ T, const unsigned char* __restrict__ choice,
    const float* __restrict__ dpfin, const int* __restrict__ lens,
    int* __restrict__ out)
{
    __shared__ unsigned char comp[Ln * Kn];   // 38912 B
    __shared__ int vchain[17];
    __shared__ int s_last, s_len;

    const int b = blockIdx.x;
    const int tid = threadIdx.x;

    {
        const int4* src = (const int4*)(choice + (size_t)b * Ln * Kn);
        int4* dst = (int4*)comp;
        for (int i = tid; i < (Ln * Kn) / 16; i += 384) dst[i] = src[i];
    }
    if (tid == 0) {
        s_len = lens[b];
        float bestv = dpfin[b * Kn + 0] + T[PAD_IDn * Kn + 0];
        int bl = 0;
        for (int ci = 1; ci < Kn; ++ci) {
            float v = dpfin[b * Kn + ci] + T[PAD_IDn * Kn + ci];
            if (v > bestv) { bestv = v; bl = ci; }
        }
        s_last = bl;
    }
    __syncthreads();
    const int len = s_len;

    // Phase 1: suffix-compose within each 128-step chunk, in place.
    {
        const int wv = tid >> 6;
        const int lane = tid & 63;
        const int ch = wv * 3 + lane / Kn;
        const int c = lane % Kn;
        if (lane < 3 * Kn && ch < 16) {
            int cur = c;
            const int tb = ch * 128 + 127;
            for (int i = 0; i < 128; ++i) {
                const int t = tb - i;
                int nv = comp[t * Kn + cur];   // cur <= 18 always: in-bounds
                cur = (t < len) ? nv : cur;
                comp[t * Kn + c] = cur;
            }
        }
    }
    __syncthreads();

    // Phase 2: chunk-boundary chain
    if (tid == 0) {
        int v = s_last;
        vchain[16] = v;
        for (int ch = 15; ch >= 0; --ch) {
            v = comp[ch * 128 * Kn + v];
            vchain[ch] = v;
        }
    }
    __syncthreads();

    // Phase 3: emit path
    const int last = s_last;
    int* orow = out + (size_t)b * Ln;
    for (int t = tid; t < Ln; t += 384) {
        int val;
        if (t >= len) {
            val = -1;
        } else if (t == Ln - 1) {
            val = last;
        } else {
            const int tp = t + 1;
            const int vc = vchain[(tp >> 7) + 1];
            val = comp[tp * Kn + vc];
        }
        orow[t] = val;
    }
}

// ---------------------------------------------------------------------------
extern "C" void kernel_launch(void* const* d_in, const int* in_sizes, int n_in,
                              void* d_out, int out_size, void* d_ws, size_t ws_size,
                              hipStream_t stream)
{
    const float* P    = (const float*)d_in[0];
    const float* T    = (const float*)d_in[1];
    const int*   mask = (const int*)d_in[2];
    int* out = (int*)d_out;

    // workspace layout — identical footprint to R1-R3/R5 (proven ok)
    const size_t choice_bytes = (size_t)Bn * Ln * Kn;            // 19,922,944
    unsigned char* choice = (unsigned char*)d_ws;
    float* dpfin = (float*)((char*)d_ws + choice_bytes);
    int* lens = (int*)((char*)d_ws + choice_bytes + (size_t)Bn * Kn * 4);

    // dpck (1,245,184 B) lives in d_out (4 MB of int32): written by crf_fwd,
    // read by crf_rec, then d_out fully overwritten by crf_bwd (R5-proven).
    float* dpck = (float*)((char*)d_out + 2 * 1024 * 1024);

    crf_fwd<<<Bn / 2, 64, 0, stream>>>(P, T, mask, dpck, dpfin, lens);
    crf_rec<<<(Bn * 32) / 8, 256, 0, stream>>>(P, T, dpck, lens, choice);
    crf_bwd<<<Bn, 384, 0, stream>>>(T, choice, dpfin, lens, out);
}

// Round 9
// 398.810 us; speedup vs baseline: 1.1912x; 1.0419x over previous
//
#include <hip/hip_runtime.h>

#define Bn 512
#define Ln 2048
#define Kn 19
#define NEGV (-1000.0f)
#define START_IDn 17
#define PAD_IDn 18
#define SEG 64               // checkpoint / staging segment (steps)
#define PBYTES 79691776u     // 512*2048*19*4

// ---------------------------------------------------------------------------
// R9 = proven crf_fwd (236-240 µs) + FUSED crf_recbt (rec+bwd in one kernel,
// one block per batch): backpointers land directly in LDS comp[], removing
// the 20 MB global choice round-trip and the separate bwd kernel (measured
// ~90 µs across R1-R3) + one launch. 512 threads/block keeps occupancy at
// ~2 blocks/CU (R8 lesson: occupancy >> instruction count for these
// latency-chain kernels).
// ---------------------------------------------------------------------------

// Shared per-step core: cand[p] = dp[p] + Trow[p] (exact reference op order),
// best = depth-3 max tree (v_max3).
#define DP_CORE(BASE)                                                          \
    float4 q0 = *(const float4*)((BASE) + 0);                                  \
    float4 q1 = *(const float4*)((BASE) + 4);                                  \
    float4 q2 = *(const float4*)((BASE) + 8);                                  \
    float4 q3 = *(const float4*)((BASE) + 12);                                 \
    float4 q4 = *(const float4*)((BASE) + 16); /* .w junk, unused */           \
    float cand[Kn];                                                            \
    cand[0]  = q0.x + Trow[0];  cand[1]  = q0.y + Trow[1];                     \
    cand[2]  = q0.z + Trow[2];  cand[3]  = q0.w + Trow[3];                     \
    cand[4]  = q1.x + Trow[4];  cand[5]  = q1.y + Trow[5];                     \
    cand[6]  = q1.z + Trow[6];  cand[7]  = q1.w + Trow[7];                     \
    cand[8]  = q2.x + Trow[8];  cand[9]  = q2.y + Trow[9];                     \
    cand[10] = q2.z + Trow[10]; cand[11] = q2.w + Trow[11];                    \
    cand[12] = q3.x + Trow[12]; cand[13] = q3.y + Trow[13];                    \
    cand[14] = q3.z + Trow[14]; cand[15] = q3.w + Trow[15];                    \
    cand[16] = q4.x + Trow[16]; cand[17] = q4.y + Trow[17];                    \
    cand[18] = q4.z + Trow[18];                                                \
    float m0 = fmaxf(fmaxf(cand[0],  cand[1]),  cand[2]);                      \
    float m1 = fmaxf(fmaxf(cand[3],  cand[4]),  cand[5]);                      \
    float m2 = fmaxf(fmaxf(cand[6],  cand[7]),  cand[8]);                      \
    float m3 = fmaxf(fmaxf(cand[9],  cand[10]), cand[11]);                     \
    float m4 = fmaxf(fmaxf(cand[12], cand[13]), cand[14]);                     \
    float m5 = fmaxf(fmaxf(cand[15], cand[16]), cand[17]);                     \
    float n0 = fmaxf(fmaxf(m0, m1), m2);                                       \
    float n1 = fmaxf(fmaxf(m3, m4), cand[18]);                                 \
    float best = fmaxf(fmaxf(n0, n1), m5);

// ---------------------------------------------------------------------------
// crf_fwd — verbatim R5/R8 (proven 236-240 µs).
// ---------------------------------------------------------------------------
__global__ __launch_bounds__(64, 1) void crf_fwd(
    const float* __restrict__ P, const float* __restrict__ T,
    const int* __restrict__ mask, float* __restrict__ dpck,
    float* __restrict__ dpfin, int* __restrict__ lens)
{
    const int lane = threadIdx.x;
    const int half = lane >> 5;
    const int c = lane & 31;
    const int b = blockIdx.x * 2 + half;
    const int cc = (c < Kn) ? c : (Kn - 1);

    float Trow[Kn];
#pragma unroll
    for (int p = 0; p < Kn; ++p) Trow[p] = T[cc * Kn + p];

    // length = popcount of contiguous-prefix mask row
    const int* mrow = mask + (size_t)b * Ln;
    int sum = 0;
#pragma unroll
    for (int j = 0; j < Ln / 128; ++j) {
        int4 v = *(const int4*)(mrow + j * 128 + c * 4);
        sum += v.x + v.y + v.z + v.w;
    }
#pragma unroll
    for (int k = 1; k < 32; k <<= 1) sum += __shfl_xor(sum, k, 64);
    const int len = sum;
    if (c == 0) lens[b] = len;
    const int lenO = __shfl_xor(len, 32, 64);
    int maxlen = len > lenO ? len : lenO;
    int lmin = len < lenO ? len : lenO;
    lmin = __builtin_amdgcn_readfirstlane(lmin);
    int mlen = (maxlen + (SEG - 1)) & ~(SEG - 1);
    mlen = __builtin_amdgcn_readfirstlane(mlen);

    __shared__ float dp[2][32];
    __shared__ float ebuf[2][2][1280];   // [buf][half]; 64*19=1216 used + pad

    float mydp = (c == START_IDn) ? 0.0f : NEGV;
    dp[half][c] = mydp;

    const unsigned bbyte = (unsigned)b * (Ln * Kn * 4u);
    const unsigned limit = PBYTES - 16;
    const char* Pc = (const char*)P;
    float4 r[10];

#define STAGE_LOAD(ci)                                                         \
    { unsigned base_ = bbyte + (unsigned)(ci) * 4864u + ((unsigned)c << 4);    \
      _Pragma("unroll")                                                        \
      for (int i_ = 0; i_ < 10; ++i_) {                                        \
          unsigned o_ = base_ + (unsigned)i_ * 512u;                           \
          if (o_ > limit) o_ = limit;                                          \
          r[i_] = *(const float4*)(Pc + o_);                                   \
      } }
#define STAGE_WRITE(nb)                                                        \
    { float* d_ = &ebuf[nb][half][(unsigned)c << 2];                           \
      _Pragma("unroll")                                                        \
      for (int i_ = 0; i_ < 10; ++i_) *(float4*)(d_ + i_ * 128) = r[i_]; }

    int buf = 0;
    STAGE_LOAD(0);
    STAGE_WRITE(0);

    for (int t0 = 0; t0 < mlen; t0 += SEG) {
        // checkpoint: DP entering step t0 (includes initial DP at t0=0)
        if (c < Kn)
            dpck[((unsigned)b * 32u + (unsigned)(t0 >> 6)) * (unsigned)Kn + (unsigned)c] = mydp;
        STAGE_LOAD((t0 >> 6) + 1);       // prefetch next segment's emissions
        const float* ebl = &ebuf[buf][half][0];

        if (t0 + SEG <= lmin) {
            // fast path: every step strictly below both lengths — no mask
            for (int tt = 0; tt < SEG; tt += 8) {
#pragma unroll
                for (int u = 0; u < 8; ++u) {
                    const float e = ebl[(tt + u) * Kn + cc];
                    const float* base_ = &dp[half][0];
                    DP_CORE(base_)
                    mydp = best + e;
                    dp[half][c] = mydp;
                }
            }
        } else {
            for (int tt = 0; tt < SEG; tt += 8) {
#pragma unroll
                for (int u = 0; u < 8; ++u) {
                    const int t = t0 + tt + u;
                    const float e = ebl[(tt + u) * Kn + cc];
                    const float* base_ = &dp[half][0];
                    DP_CORE(base_)
                    float nd = best + e;
                    mydp = (t < len) ? nd : mydp;   // frozen past sequence end
                    dp[half][c] = mydp;
                }
            }
        }
        STAGE_WRITE(buf ^ 1);
        buf ^= 1;
    }
    if (c < Kn) dpfin[b * Kn + c] = mydp;
#undef STAGE_LOAD
#undef STAGE_WRITE
}

// ---------------------------------------------------------------------------
// crf_recbt — FUSED recompute + backtrace. One block per batch, 512 threads
// (16 half-waves x 2 passes = 32 segments). Backpointers written directly to
// LDS comp[]; then in-block function-composition backtrace (proven logic):
//   phase 1: per-chunk suffix compose in place (identity for t >= len)
//   phase 2: 16-step chunk-boundary chain
//   phase 3: parallel path emission.
// LDS: comp 38912 + dp 2048 + misc ~ 41 KB -> 2 blocks/CU (threads: 2048/512
// = 4, LDS: 160/41 = 3, VGPR ~88: 20 waves/CU -> 2 blocks).
// ---------------------------------------------------------------------------
__global__ __launch_bounds__(512, 1) void crf_recbt(
    const float* __restrict__ P, const float* __restrict__ T,
    const float* __restrict__ dpck, const float* __restrict__ dpfin,
    const int* __restrict__ lens, int* __restrict__ out)
{
    const int tid = threadIdx.x;
    const int b = blockIdx.x;
    const int hw = tid >> 5;                  // 0..15 half-wave id
    const int c = tid & 31;
    const int cc = (c < Kn) ? c : (Kn - 1);
    const int len = lens[b];

    __shared__ unsigned char comp[Ln * Kn];   // 38912 B
    __shared__ float dp[16][32];              // 2 KB, 128B rows
    __shared__ int vchain[17];
    __shared__ int s_last;

    float Trow[Kn];
#pragma unroll
    for (int p = 0; p < Kn; ++p) Trow[p] = T[cc * Kn + p];

    // --- segment recompute: bit-exact replay from checkpoints -------------
#pragma unroll 1
    for (int pass = 0; pass < 2; ++pass) {
        const int seg = hw + pass * 16;       // 0..31
        const int t0 = seg * SEG;
        if (t0 < len) {
            float mydp = (c < Kn)
                ? dpck[((unsigned)b * 32u + (unsigned)seg) * (unsigned)Kn + (unsigned)c]
                : NEGV;
            dp[hw][c] = mydp;
            const float* prow = P + (size_t)b * Ln * Kn + (size_t)t0 * Kn;

            float eb[8];                      // rolling emission prefetch
#pragma unroll
            for (int u = 0; u < 8; ++u) eb[u] = prow[u * Kn + cc];

            for (int tt = 0; tt < SEG; tt += 8) {
#pragma unroll
                for (int u = 0; u < 8; ++u) {
                    const int t = t0 + tt + u;
                    const float e = eb[u];
                    const float* base_ = &dp[hw][0];
                    DP_CORE(base_)
                    float nd = best + e;
                    mydp = (t < len) ? nd : mydp;
                    dp[hw][c] = mydp;

                    // first-index argmax (jnp.argmax tie-break)
                    int arg = Kn - 1;
#pragma unroll
                    for (int p = Kn - 2; p >= 0; --p)
                        arg = (cand[p] == best) ? p : arg;
                    if (c < Kn) comp[t * Kn + c] = (unsigned char)arg;

                    int tn = tt + u + 8;      // clamped in-bounds prefetch
                    int tloc = (t0 + tn < Ln) ? tn : (Ln - 1 - t0);
                    eb[u] = prow[tloc * Kn + cc];
                }
            }
        }
        // segments with t0 >= len leave comp rows stale; phase 1 writes
        // identity into all rows t >= len, so stale bytes are never used.
    }
    __syncthreads();

    // --- phase 1: suffix-compose within each 128-step chunk, in place -----
    // 8 waves x 2 chunks (lanes 0..37). Reads precede writes in lockstep.
    // Concurrently, tid 511 (lane 63, inactive in phase 1) computes s_last.
    {
        const int wv = tid >> 6;              // 0..7
        const int lane = tid & 63;
        if (lane < 2 * Kn) {
            const int ch = wv * 2 + lane / Kn;     // 0..15
            const int c2 = lane % Kn;
            int cur = c2;
            const int tb = ch * 128 + 127;
            for (int i = 0; i < 128; ++i) {
                const int t = tb - i;
                int nv = comp[t * Kn + cur];  // cur <= 18 always: in-bounds
                cur = (t < len) ? nv : cur;   // g_t = id for t >= len
                comp[t * Kn + c2] = cur;
            }
        } else if (tid == 511) {
            // last = argmax_c( DPfinal[c] + T[PAD][c] ), first-index tie-break
            float bestv = dpfin[b * Kn + 0] + T[PAD_IDn * Kn + 0];
            int bl = 0;
            for (int ci = 1; ci < Kn; ++ci) {
                float v = dpfin[b * Kn + ci] + T[PAD_IDn * Kn + ci];
                if (v > bestv) { bestv = v; bl = ci; }
            }
            s_last = bl;
        }
    }
    __syncthreads();

    // --- phase 2: chunk-boundary chain ------------------------------------
    if (tid == 0) {
        int v = s_last;
        vchain[16] = v;
        for (int ch = 15; ch >= 0; --ch) {
            v = comp[ch * 128 * Kn + v];
            vchain[ch] = v;
        }
    }
    __syncthreads();

    // --- phase 3: emit path ------------------------------------------------
    const int last = s_last;
    int* orow = out + (size_t)b * Ln;
    for (int t = tid; t < Ln; t += 512) {
        int val;
        if (t >= len) {
            val = -1;
        } else if (t == Ln - 1) {
            val = last;                        // only reachable when len == L
        } else {
            const int tp = t + 1;
            const int vc = vchain[(tp >> 7) + 1];
            val = comp[tp * Kn + vc];
        }
        orow[t] = val;
    }
}

// ---------------------------------------------------------------------------
extern "C" void kernel_launch(void* const* d_in, const int* in_sizes, int n_in,
                              void* d_out, int out_size, void* d_ws, size_t ws_size,
                              hipStream_t stream)
{
    const float* P    = (const float*)d_in[0];
    const float* T    = (const float*)d_in[1];
    const int*   mask = (const int*)d_in[2];
    int* out = (int*)d_out;

    // workspace layout — 1.29 MB total (choice buffer eliminated by fusion)
    float* dpck  = (float*)d_ws;                                  // 1,245,184 B
    float* dpfin = (float*)((char*)d_ws + (size_t)Bn * 32 * Kn * 4);
    int*   lens  = (int*)((char*)d_ws + (size_t)Bn * 32 * Kn * 4
                          + (size_t)Bn * Kn * 4);

    crf_fwd<<<Bn / 2, 64, 0, stream>>>(P, T, mask, dpck, dpfin, lens);
    crf_recbt<<<Bn, 512, 0, stream>>>(P, T, dpck, dpfin, lens, out);
}